// Round 1
// baseline (310.853 us; speedup 1.0000x reference)
//
#include <hip/hip_runtime.h>
#include <cstdint>
#include <cstddef>

// Problem constants
#define Bb 2
#define Nn 2048
#define DIMM 1024
#define Hh 16
#define DHh 64
#define BH (Bb*Hh)        // 32
#define MROWS (Bb*Nn)     // 4096

typedef __bf16 bf16x8 __attribute__((ext_vector_type(8)));
typedef float f32x4 __attribute__((ext_vector_type(4)));

__device__ __forceinline__ unsigned short f2bf(float f) {
  unsigned u = __float_as_uint(f);
  u += 0x7FFFu + ((u >> 16) & 1u);       // RNE
  return (unsigned short)(u >> 16);
}
__device__ __forceinline__ float bf2f(unsigned short s) {
  return __uint_as_float(((unsigned)s) << 16);
}

// async global->LDS, 16B per lane; LDS dest must be wave-uniform-base + lane*16
#define GLDS16(g, l) __builtin_amdgcn_global_load_lds( \
    (const __attribute__((address_space(1))) void*)(g), \
    (__attribute__((address_space(3))) void*)(l), 16, 0, 0)

// ---------------------------------------------------------------------------
// LayerNorm: x fp32 [4096,1024] -> y bf16. One block per row.
__global__ __launch_bounds__(256) void ln_kernel(
    const float* __restrict__ x, const float* __restrict__ g,
    const float* __restrict__ b, unsigned short* __restrict__ y) {
  int row = blockIdx.x;
  int t = threadIdx.x;
  const float4* xr = (const float4*)(x + (size_t)row * DIMM);
  float4 v = xr[t];
  float s  = v.x + v.y + v.z + v.w;
  float ss = v.x*v.x + v.y*v.y + v.z*v.z + v.w*v.w;
  #pragma unroll
  for (int o = 1; o < 64; o <<= 1) { s += __shfl_xor(s, o); ss += __shfl_xor(ss, o); }
  __shared__ float red[8];
  int wv = t >> 6;
  if ((t & 63) == 0) { red[wv] = s; red[wv + 4] = ss; }
  __syncthreads();
  s  = red[0] + red[1] + red[2] + red[3];
  ss = red[4] + red[5] + red[6] + red[7];
  float mu  = s * (1.0f / DIMM);
  float var = ss * (1.0f / DIMM) - mu * mu;
  float rs  = rsqrtf(var + 1e-5f);
  float4 gv = ((const float4*)g)[t];
  float4 bv = ((const float4*)b)[t];
  ushort4 o4;
  o4.x = f2bf((v.x - mu) * rs * gv.x + bv.x);
  o4.y = f2bf((v.y - mu) * rs * gv.y + bv.y);
  o4.z = f2bf((v.z - mu) * rs * gv.z + bv.z);
  o4.w = f2bf((v.w - mu) * rs * gv.w + bv.w);
  ((ushort4*)y)[(size_t)row * 256 + t] = o4;
}

// ---------------------------------------------------------------------------
// Transpose + fp32->bf16: in [R][C] -> out [C][R]
__global__ void transpose_conv(const float* __restrict__ in,
                               unsigned short* __restrict__ out, int R, int C) {
  __shared__ float tile[32][33];
  int tx = threadIdx.x, ty = threadIdx.y;
  int x  = blockIdx.x * 32 + tx;
  int y0 = blockIdx.y * 32;
  #pragma unroll
  for (int j = 0; j < 32; j += 8)
    tile[ty + j][tx] = in[(size_t)(y0 + ty + j) * C + x];
  __syncthreads();
  int ox  = blockIdx.y * 32 + tx;
  int oy0 = blockIdx.x * 32;
  #pragma unroll
  for (int j = 0; j < 32; j += 8)
    out[(size_t)(oy0 + ty + j) * R + ox] = f2bf(tile[tx][ty + j]);
}

// Elementwise fp32->bf16 (for to_out_w, already [n,k])
__global__ void convert_bf(const float* __restrict__ in, unsigned short* __restrict__ out) {
  int i = (blockIdx.x * blockDim.x + threadIdx.x) * 4;
  float4 v = *(const float4*)(in + i);
  ushort4 o;
  o.x = f2bf(v.x); o.y = f2bf(v.y); o.z = f2bf(v.z); o.w = f2bf(v.w);
  *(ushort4*)(out + i) = o;
}

// ---------------------------------------------------------------------------
// NT GEMM: C[M,N] = A[M,K] * Bt[N,K]^T (+bias). 128x128 tile, BK=32, 4 waves.
// EPI 0: scatter qkv -> q/k/v [B,H,N,DH] bf16
// EPI 1: bf16 out [M,N] with bias
// EPI 2: fp32 out [M,N] no bias
template <int EPI>
__global__ __launch_bounds__(256) void gemm_nt(
    const unsigned short* __restrict__ A, const unsigned short* __restrict__ Bt,
    const float* __restrict__ bias,
    unsigned short* __restrict__ obf, float* __restrict__ of32,
    unsigned short* __restrict__ q_std, unsigned short* __restrict__ k_std,
    unsigned short* __restrict__ v_std,
    int M, int N, int K) {
  __shared__ unsigned short sA[128 * 32];
  __shared__ unsigned short sB[128 * 32];
  int t = threadIdx.x;
  int bn = blockIdx.x, bm = blockIdx.y;
  int lane = t & 63, wv = t >> 6;
  int wm = (wv >> 1) * 64, wn = (wv & 1) * 64;
  int l16 = lane & 15, quad = lane >> 4;

  const unsigned short* Ab = A + (size_t)(bm * 128) * K;
  const unsigned short* Bb2 = Bt + (size_t)(bn * 128) * K;
  int row0 = t >> 2, kc0 = (t & 3) * 8;   // 4 chunks of 8 elems per 32-wide row

  f32x4 acc[4][4] = {};

  for (int kt = 0; kt < K; kt += 32) {
    __syncthreads();
    GLDS16(Ab  + (size_t)row0        * K + kt + kc0, sA + (size_t)t * 8);
    GLDS16(Ab  + (size_t)(row0 + 64) * K + kt + kc0, sA + (size_t)(t + 256) * 8);
    GLDS16(Bb2 + (size_t)row0        * K + kt + kc0, sB + (size_t)t * 8);
    GLDS16(Bb2 + (size_t)(row0 + 64) * K + kt + kc0, sB + (size_t)(t + 256) * 8);
    __syncthreads();
    bf16x8 af[4], bfr[4];
    #pragma unroll
    for (int i = 0; i < 4; i++)
      af[i] = *(const bf16x8*)(sA + (wm + i * 16 + l16) * 32 + quad * 8);
    #pragma unroll
    for (int j = 0; j < 4; j++)
      bfr[j] = *(const bf16x8*)(sB + (wn + j * 16 + l16) * 32 + quad * 8);
    #pragma unroll
    for (int i = 0; i < 4; i++)
      #pragma unroll
      for (int j = 0; j < 4; j++)
        acc[i][j] = __builtin_amdgcn_mfma_f32_16x16x32_bf16(af[i], bfr[j], acc[i][j], 0, 0, 0);
  }

  // epilogue: D row = quad*4+reg, col = l16
  #pragma unroll
  for (int i = 0; i < 4; i++) {
    #pragma unroll
    for (int j = 0; j < 4; j++) {
      int n = bn * 128 + wn + j * 16 + l16;
      float bval = (EPI == 2) ? 0.0f : bias[n];
      #pragma unroll
      for (int r = 0; r < 4; r++) {
        int m = bm * 128 + wm + i * 16 + quad * 4 + r;
        float val = acc[i][j][r] + bval;
        if (EPI == 0) {
          int which = n >> 10, nn2 = n & 1023;
          int h = nn2 >> 6, d = nn2 & 63;
          int bi = m >> 11, ns = m & 2047;
          unsigned short* dst = (which == 0) ? q_std : ((which == 1) ? k_std : v_std);
          dst[((size_t)((bi * Hh + h) * Nn + ns)) * DHh + d] = f2bf(val);
        } else if (EPI == 1) {
          obf[(size_t)m * N + n] = f2bf(val);
        } else {
          of32[(size_t)m * N + n] = val;
        }
      }
    }
  }
}

// ---------------------------------------------------------------------------
// L2 normalize rows of q (scale 8 folded) and k, in place. One wave per row.
__global__ __launch_bounds__(256) void l2norm_kernel(
    unsigned short* __restrict__ q, unsigned short* __restrict__ k) {
  int t = threadIdx.x, lane = t & 63, wv = t >> 6;
  long task = (long)blockIdx.x * 4 + wv;   // 0 .. 2*65536-1
  unsigned short* base;
  float scale;
  if (task < (long)BH * Nn) { base = q + task * DHh; scale = 8.0f; }
  else { base = k + (task - (long)BH * Nn) * DHh; scale = 1.0f; }
  float v = bf2f(base[lane]);
  float ss = v * v;
  #pragma unroll
  for (int o = 1; o < 64; o <<= 1) ss += __shfl_xor(ss, o);
  float nrm = sqrtf(ss);
  float s = scale / fmaxf(nrm, 1e-12f);
  base[lane] = f2bf(v * s);
}

// ---------------------------------------------------------------------------
// Transpose V: [B,H,N,DH] -> [B,H,DH,N] (bf16)
__global__ void transpose_v(const unsigned short* __restrict__ v,
                            unsigned short* __restrict__ vt) {
  __shared__ unsigned short tile[32][33];
  int bh = blockIdx.z;
  const unsigned short* in = v + (size_t)bh * Nn * DHh;
  unsigned short* out = vt + (size_t)bh * DHh * Nn;
  int tx = threadIdx.x, ty = threadIdx.y;
  int x = blockIdx.x * 32 + tx;        // d
  int y0 = blockIdx.y * 32;            // n
  #pragma unroll
  for (int j = 0; j < 32; j += 8)
    tile[ty + j][tx] = in[(size_t)(y0 + ty + j) * DHh + x];
  __syncthreads();
  int ox = blockIdx.y * 32 + tx;       // n
  int oy0 = blockIdx.x * 32;           // d
  #pragma unroll
  for (int j = 0; j < 32; j += 8)
    out[(size_t)(oy0 + ty + j) * Nn + ox] = tile[tx][ty + j];
}

// ---------------------------------------------------------------------------
// Causal cosine-sim attention (flash-style, fixed shift: logits <= 8 exactly).
// Grid (16 qblocks, 32 bh). 4 waves x 32 q-rows = 128 q-rows / block.
__global__ __launch_bounds__(256) void attn_kernel(
    const unsigned short* __restrict__ qn, const unsigned short* __restrict__ kn,
    const unsigned short* __restrict__ vt, unsigned short* __restrict__ o_flat) {
  __shared__ unsigned short sK[64 * 64];
  __shared__ unsigned short sV[64 * 64];        // V^T tile: [d][j]
  __shared__ unsigned short sP[4][32 * 64];
  int t = threadIdx.x, lane = t & 63, wv = t >> 6;
  int l16 = lane & 15, quad = lane >> 4;
  int qb = blockIdx.x, bh = blockIdx.y;
  int m0 = qb * 128 + wv * 32;                  // wave's first q row (seq index)
  const unsigned short* qbase = qn + (size_t)bh * Nn * DHh;
  const unsigned short* kbase = kn + (size_t)bh * Nn * DHh;
  const unsigned short* vbase = vt + (size_t)bh * DHh * Nn;

  // Q fragments in registers for the whole K loop (q pre-scaled by 8)
  bf16x8 aq[2][2];
  #pragma unroll
  for (int i2 = 0; i2 < 2; i2++)
    #pragma unroll
    for (int kk = 0; kk < 2; kk++)
      aq[i2][kk] = *(const bf16x8*)(qbase + (size_t)(m0 + i2 * 16 + l16) * DHh + kk * 32 + quad * 8);

  f32x4 accO[2][4] = {};
  float den[2][4] = {};

  int krow = t >> 3, koff = (t & 7) * 8;   // 8 chunks of 8 elems per 64-wide row
  unsigned short* pw = sP[wv];
  int nkt = qb * 2 + 2;

  for (int kt = 0; kt < nkt; kt++) {
    int j0 = kt * 64;
    __syncthreads();
    GLDS16(kbase + (size_t)(j0 + krow)      * DHh + koff, sK + (size_t)t * 8);
    GLDS16(kbase + (size_t)(j0 + krow + 32) * DHh + koff, sK + (size_t)(t + 256) * 8);
    GLDS16(vbase + (size_t)krow        * Nn + j0 + koff, sV + (size_t)t * 8);
    GLDS16(vbase + (size_t)(krow + 32) * Nn + j0 + koff, sV + (size_t)(t + 256) * 8);
    __syncthreads();

    // S = Qn * Kn^T   (32 q-rows x 64 j per wave)
    f32x4 sc[2][4] = {};
    #pragma unroll
    for (int kk = 0; kk < 2; kk++) {
      #pragma unroll
      for (int jt = 0; jt < 4; jt++) {
        bf16x8 bk = *(const bf16x8*)(sK + (jt * 16 + l16) * 64 + kk * 32 + quad * 8);
        #pragma unroll
        for (int i2 = 0; i2 < 2; i2++)
          sc[i2][jt] = __builtin_amdgcn_mfma_f32_16x16x32_bf16(aq[i2][kk], bk, sc[i2][jt], 0, 0, 0);
      }
    }

    // mask, exp(s-8), den accumulate, write P (bf16) to LDS in row-major
    #pragma unroll
    for (int i2 = 0; i2 < 2; i2++) {
      #pragma unroll
      for (int jt = 0; jt < 4; jt++) {
        int j = j0 + jt * 16 + l16;
        #pragma unroll
        for (int r = 0; r < 4; r++) {
          int qrow = m0 + i2 * 16 + quad * 4 + r;
          float p = (j <= qrow) ? __expf(sc[i2][jt][r] - 8.0f) : 0.0f;
          unsigned short pb = f2bf(p);
          den[i2][r] += bf2f(pb);   // accumulate the rounded value (matches PV numerator)
          pw[(i2 * 16 + quad * 4 + r) * 64 + jt * 16 + l16] = pb;
        }
      }
    }
    __syncthreads();

    // O += P * V  (P from LDS A-layout, V^T from LDS B-layout)
    #pragma unroll
    for (int kk = 0; kk < 2; kk++) {
      bf16x8 pa[2];
      #pragma unroll
      for (int i2 = 0; i2 < 2; i2++)
        pa[i2] = *(const bf16x8*)(pw + (i2 * 16 + l16) * 64 + kk * 32 + quad * 8);
      #pragma unroll
      for (int dt = 0; dt < 4; dt++) {
        bf16x8 bv = *(const bf16x8*)(sV + (dt * 16 + l16) * 64 + kk * 32 + quad * 8);
        #pragma unroll
        for (int i2 = 0; i2 < 2; i2++)
          accO[i2][dt] = __builtin_amdgcn_mfma_f32_16x16x32_bf16(pa[i2], bv, accO[i2][dt], 0, 0, 0);
      }
    }
  }

  // reduce den across the 16 lanes of each quad (j-direction)
  #pragma unroll
  for (int i2 = 0; i2 < 2; i2++)
    #pragma unroll
    for (int r = 0; r < 4; r++) {
      float d = den[i2][r];
      #pragma unroll
      for (int o = 1; o < 16; o <<= 1) d += __shfl_xor(d, o);
      den[i2][r] = 1.0f / d;
    }

  // write O -> o_flat [B,N,DIM] bf16 (merge heads)
  int bi = bh >> 4, h = bh & 15;
  #pragma unroll
  for (int i2 = 0; i2 < 2; i2++)
    #pragma unroll
    for (int dt = 0; dt < 4; dt++)
      #pragma unroll
      for (int r = 0; r < 4; r++) {
        int ns = m0 + i2 * 16 + quad * 4 + r;
        o_flat[((size_t)(bi * Nn + ns)) * DIMM + h * DHh + dt * 16 + l16] =
            f2bf(accO[i2][dt][r] * den[i2][r]);
      }
}

// ---------------------------------------------------------------------------
extern "C" void kernel_launch(void* const* d_in, const int* in_sizes, int n_in,
                              void* d_out, int out_size, void* d_ws, size_t ws_size,
                              hipStream_t stream) {
  const float* x        = (const float*)d_in[0];
  const float* g        = (const float*)d_in[1];
  const float* b        = (const float*)d_in[2];
  const float* c_attn_w = (const float*)d_in[3];
  const float* c_attn_b = (const float*)d_in[4];
  const float* c_proj_w = (const float*)d_in[5];
  const float* c_proj_b = (const float*)d_in[6];
  const float* to_out_w = (const float*)d_in[7];
  float* out = (float*)d_out;

  char* p = (char*)d_ws;
  // layout (MB offsets); y reused as o_flat, q reused as t-buffer
  unsigned short* y     = (unsigned short*)(p + ((size_t)0  << 20)); // 8 MB
  unsigned short* qbuf  = (unsigned short*)(p + ((size_t)8  << 20)); // 8 MB
  unsigned short* kbuf  = (unsigned short*)(p + ((size_t)16 << 20)); // 8 MB
  unsigned short* vbuf  = (unsigned short*)(p + ((size_t)24 << 20)); // 8 MB
  unsigned short* vtb   = (unsigned short*)(p + ((size_t)32 << 20)); // 8 MB
  unsigned short* wqkv  = (unsigned short*)(p + ((size_t)40 << 20)); // 6 MB
  unsigned short* wproj = (unsigned short*)(p + ((size_t)46 << 20)); // 2 MB
  unsigned short* wout  = (unsigned short*)(p + ((size_t)48 << 20)); // 2 MB

  // 1. LayerNorm -> y (bf16)
  ln_kernel<<<MROWS, 256, 0, stream>>>(x, g, b, y);
  // 2. weight conversion
  transpose_conv<<<dim3(3 * DIMM / 32, DIMM / 32), dim3(32, 8), 0, stream>>>(c_attn_w, wqkv, DIMM, 3 * DIMM);
  transpose_conv<<<dim3(DIMM / 32, DIMM / 32), dim3(32, 8), 0, stream>>>(c_proj_w, wproj, DIMM, DIMM);
  convert_bf<<<(DIMM * DIMM) / (256 * 4), 256, 0, stream>>>(to_out_w, wout);
  // 3. qkv GEMM + scatter
  gemm_nt<0><<<dim3(3 * DIMM / 128, MROWS / 128), 256, 0, stream>>>(
      y, wqkv, c_attn_b, nullptr, nullptr, qbuf, kbuf, vbuf, MROWS, 3 * DIMM, DIMM);
  // 4. l2norm q (x8) and k
  l2norm_kernel<<<(2 * BH * Nn) / 4, 256, 0, stream>>>(qbuf, kbuf);
  // 5. V transpose
  transpose_v<<<dim3(DHh / 32, Nn / 32, BH), dim3(32, 8), 0, stream>>>(vbuf, vtb);
  // 6. attention -> o_flat (reuses y)
  attn_kernel<<<dim3(Nn / 128, BH), 256, 0, stream>>>(qbuf, kbuf, vtb, y);
  // 7. c_proj GEMM -> t (reuses qbuf)
  gemm_nt<1><<<dim3(DIMM / 128, MROWS / 128), 256, 0, stream>>>(
      y, wproj, c_proj_b, qbuf, nullptr, nullptr, nullptr, nullptr, MROWS, DIMM, DIMM);
  // 8. to_out GEMM (NT, to_out_w already [n,k]) -> fp32 out
  gemm_nt<2><<<dim3(DIMM / 128, MROWS / 128), 256, 0, stream>>>(
      qbuf, wout, nullptr, nullptr, out, nullptr, nullptr, nullptr, MROWS, DIMM, DIMM);
}

// Round 2
// 262.104 us; speedup vs baseline: 1.1860x; 1.1860x over previous
//
#include <hip/hip_runtime.h>
#include <cstdint>
#include <cstddef>

// Problem constants
#define Bb 2
#define Nn 2048
#define DIMM 1024
#define Hh 16
#define DHh 64
#define BH (Bb*Hh)        // 32
#define MROWS (Bb*Nn)     // 4096

typedef __bf16 bf16x8 __attribute__((ext_vector_type(8)));
typedef float f32x4 __attribute__((ext_vector_type(4)));

__device__ __forceinline__ unsigned short f2bf(float f) {
  unsigned u = __float_as_uint(f);
  u += 0x7FFFu + ((u >> 16) & 1u);       // RNE
  return (unsigned short)(u >> 16);
}
__device__ __forceinline__ unsigned short f2bf_fast(float f) {
  return (unsigned short)((__float_as_uint(f) + 0x8000u) >> 16);
}
__device__ __forceinline__ float bf2f(unsigned short s) {
  return __uint_as_float(((unsigned)s) << 16);
}

// async global->LDS, 16B per lane; LDS dest must be wave-uniform base + lane*16
#define GLDS16(g, l) __builtin_amdgcn_global_load_lds( \
    (const __attribute__((address_space(1))) void*)(g), \
    (__attribute__((address_space(3))) void*)(l), 16, 0, 0)

// ---------------------------------------------------------------------------
// LayerNorm: x fp32 [4096,1024] -> y bf16. One block per row.
__global__ __launch_bounds__(256) void ln_kernel(
    const float* __restrict__ x, const float* __restrict__ g,
    const float* __restrict__ b, unsigned short* __restrict__ y) {
  int row = blockIdx.x;
  int t = threadIdx.x;
  const float4* xr = (const float4*)(x + (size_t)row * DIMM);
  float4 v = xr[t];
  float s  = v.x + v.y + v.z + v.w;
  float ss = v.x*v.x + v.y*v.y + v.z*v.z + v.w*v.w;
  #pragma unroll
  for (int o = 1; o < 64; o <<= 1) { s += __shfl_xor(s, o); ss += __shfl_xor(ss, o); }
  __shared__ float red[8];
  int wv = t >> 6;
  if ((t & 63) == 0) { red[wv] = s; red[wv + 4] = ss; }
  __syncthreads();
  s  = red[0] + red[1] + red[2] + red[3];
  ss = red[4] + red[5] + red[6] + red[7];
  float mu  = s * (1.0f / DIMM);
  float var = ss * (1.0f / DIMM) - mu * mu;
  float rs  = rsqrtf(var + 1e-5f);
  float4 gv = ((const float4*)g)[t];
  float4 bv = ((const float4*)b)[t];
  ushort4 o4;
  o4.x = f2bf((v.x - mu) * rs * gv.x + bv.x);
  o4.y = f2bf((v.y - mu) * rs * gv.y + bv.y);
  o4.z = f2bf((v.z - mu) * rs * gv.z + bv.z);
  o4.w = f2bf((v.w - mu) * rs * gv.w + bv.w);
  ((ushort4*)y)[(size_t)row * 256 + t] = o4;
}

// ---------------------------------------------------------------------------
// Transpose + fp32->bf16: in [R][C] -> out [C][R]
__global__ void transpose_conv(const float* __restrict__ in,
                               unsigned short* __restrict__ out, int R, int C) {
  __shared__ float tile[32][33];
  int tx = threadIdx.x, ty = threadIdx.y;
  int x  = blockIdx.x * 32 + tx;
  int y0 = blockIdx.y * 32;
  #pragma unroll
  for (int j = 0; j < 32; j += 8)
    tile[ty + j][tx] = in[(size_t)(y0 + ty + j) * C + x];
  __syncthreads();
  int ox  = blockIdx.y * 32 + tx;
  int oy0 = blockIdx.x * 32;
  #pragma unroll
  for (int j = 0; j < 32; j += 8)
    out[(size_t)(oy0 + ty + j) * R + ox] = f2bf(tile[tx][ty + j]);
}

// Elementwise fp32->bf16
__global__ void convert_bf(const float* __restrict__ in, unsigned short* __restrict__ out) {
  int i = (blockIdx.x * blockDim.x + threadIdx.x) * 4;
  float4 v = *(const float4*)(in + i);
  ushort4 o;
  o.x = f2bf(v.x); o.y = f2bf(v.y); o.z = f2bf(v.z); o.w = f2bf(v.w);
  *(ushort4*)(out + i) = o;
}

// Combined bias: bc[n] = sum_c bp[c] * Wo[n][c]   (fp32). One wave per n.
__global__ __launch_bounds__(256) void bias_comb(
    const float* __restrict__ bp, const float* __restrict__ wo,
    float* __restrict__ bc) {
  int n = blockIdx.x * 4 + (threadIdx.x >> 6);
  int lane = threadIdx.x & 63;
  const float4* w = (const float4*)(wo + (size_t)n * DIMM);
  const float4* b4 = (const float4*)bp;
  float s = 0.0f;
  #pragma unroll
  for (int k = 0; k < 4; k++) {
    float4 wv = w[lane + k * 64], bv = b4[lane + k * 64];
    s += wv.x * bv.x + wv.y * bv.y + wv.z * bv.z + wv.w * bv.w;
  }
  #pragma unroll
  for (int o = 1; o < 64; o <<= 1) s += __shfl_xor(s, o);
  if (lane == 0) bc[n] = s;
}

// ---------------------------------------------------------------------------
// NT GEMM: C[M,N] = A[M,K] * Bt[N,K]^T (+bias). 128x128 tile, BK=64, 4 waves.
// XOR-swizzled LDS (chunk ^= row&7) to kill bank conflicts.
// EPI 0: scatter qkv -> q/k/v [B,H,N,DH] bf16, with fused L2-norm (q*8, k)
// EPI 2: fp32 out [M,N] + bias
// EPI 3: bf16 out [M,N], no bias
template <int EPI>
__global__ __launch_bounds__(256) void gemm_nt(
    const unsigned short* __restrict__ A, const unsigned short* __restrict__ Bt,
    const float* __restrict__ bias,
    unsigned short* __restrict__ obf, float* __restrict__ of32,
    unsigned short* __restrict__ q_std, unsigned short* __restrict__ k_std,
    unsigned short* __restrict__ v_std,
    int M, int N, int K) {
  __shared__ unsigned short sA[128 * 64];
  __shared__ unsigned short sB[128 * 64];
  int t = threadIdx.x;
  int bn = blockIdx.x, bm = blockIdx.y;
  int lane = t & 63, wv = t >> 6;
  int wm = (wv >> 1) * 64, wn = (wv & 1) * 64;
  int l16 = lane & 15, quad = lane >> 4;

  const unsigned short* Ab = A + (size_t)(bm * 128) * K;
  const unsigned short* Bb2 = Bt + (size_t)(bn * 128) * K;
  int srow = t >> 3;                     // 0..31
  int gch = (t & 7) ^ (srow & 7);        // swizzled global chunk for this lane

  f32x4 acc[4][4] = {};

  for (int kt = 0; kt < K; kt += 64) {
    __syncthreads();
    #pragma unroll
    for (int i = 0; i < 4; i++) {
      GLDS16(Ab  + (size_t)(srow + 32 * i) * K + kt + gch * 8, sA + (size_t)(t + 256 * i) * 8);
      GLDS16(Bb2 + (size_t)(srow + 32 * i) * K + kt + gch * 8, sB + (size_t)(t + 256 * i) * 8);
    }
    __syncthreads();
    #pragma unroll
    for (int kk = 0; kk < 2; kk++) {
      int slot = (kk * 4 + quad) ^ (l16 & 7);
      bf16x8 af[4], bfr[4];
      #pragma unroll
      for (int i = 0; i < 4; i++)
        af[i] = *(const bf16x8*)(sA + (size_t)(wm + i * 16 + l16) * 64 + slot * 8);
      #pragma unroll
      for (int j = 0; j < 4; j++)
        bfr[j] = *(const bf16x8*)(sB + (size_t)(wn + j * 16 + l16) * 64 + slot * 8);
      #pragma unroll
      for (int i = 0; i < 4; i++)
        #pragma unroll
        for (int j = 0; j < 4; j++)
          acc[i][j] = __builtin_amdgcn_mfma_f32_16x16x32_bf16(af[i], bfr[j], acc[i][j], 0, 0, 0);
    }
  }

  // epilogue: D row = quad*4+reg, col = l16
  float bvals[4];
  #pragma unroll
  for (int j = 0; j < 4; j++)
    bvals[j] = (EPI == 3) ? 0.0f : bias[bn * 128 + wn + j * 16 + l16];

  if (EPI == 0) {
    int which = bn >> 3;                 // 0=q 1=k 2=v  (bn*128/1024)
    #pragma unroll
    for (int i = 0; i < 4; i++) {
      #pragma unroll
      for (int r = 0; r < 4; r++) {
        int m = bm * 128 + wm + i * 16 + quad * 4 + r;
        float vals[4];
        float ss = 0.0f;
        #pragma unroll
        for (int j = 0; j < 4; j++) {
          vals[j] = acc[i][j][r] + bvals[j];
          ss += vals[j] * vals[j];
        }
        float scale = 1.0f;
        if (which < 2) {
          ss += __shfl_xor(ss, 1); ss += __shfl_xor(ss, 2);
          ss += __shfl_xor(ss, 4); ss += __shfl_xor(ss, 8);
          scale = ((which == 0) ? 8.0f : 1.0f) / fmaxf(sqrtf(ss), 1e-12f);
        }
        int bi = m >> 11, ns = m & 2047;
        unsigned short* dst = (which == 0) ? q_std : ((which == 1) ? k_std : v_std);
        #pragma unroll
        for (int j = 0; j < 4; j++) {
          int n = bn * 128 + wn + j * 16 + l16;
          int nn2 = n & 1023;
          int h = nn2 >> 6, d = nn2 & 63;
          dst[((size_t)((bi * Hh + h) * Nn + ns)) * DHh + d] = f2bf(vals[j] * scale);
        }
      }
    }
  } else {
    #pragma unroll
    for (int i = 0; i < 4; i++) {
      #pragma unroll
      for (int j = 0; j < 4; j++) {
        int n = bn * 128 + wn + j * 16 + l16;
        #pragma unroll
        for (int r = 0; r < 4; r++) {
          int m = bm * 128 + wm + i * 16 + quad * 4 + r;
          float val = acc[i][j][r] + bvals[j];
          if (EPI == 2) of32[(size_t)m * N + n] = val;
          else          obf[(size_t)m * N + n] = f2bf(val);
        }
      }
    }
  }
}

// ---------------------------------------------------------------------------
// Transpose V: [B,H,N,DH] -> [B,H,DH,N] (bf16)
__global__ void transpose_v(const unsigned short* __restrict__ v,
                            unsigned short* __restrict__ vt) {
  __shared__ unsigned short tile[32][33];
  int bh = blockIdx.z;
  const unsigned short* in = v + (size_t)bh * Nn * DHh;
  unsigned short* out = vt + (size_t)bh * DHh * Nn;
  int tx = threadIdx.x, ty = threadIdx.y;
  int x = blockIdx.x * 32 + tx;        // d
  int y0 = blockIdx.y * 32;            // n
  #pragma unroll
  for (int j = 0; j < 32; j += 8)
    tile[ty + j][tx] = in[(size_t)(y0 + ty + j) * DHh + x];
  __syncthreads();
  int ox = blockIdx.y * 32 + tx;       // n
  int oy0 = blockIdx.x * 32;           // d
  #pragma unroll
  for (int j = 0; j < 32; j += 8)
    out[(size_t)(oy0 + ty + j) * Nn + ox] = tile[tx][ty + j];
}

// ---------------------------------------------------------------------------
// Causal cosine-sim attention (flash-style, fixed shift: logits <= 8 exactly).
// 1D grid of 512 blocks, heavy q-tiles dispatched first for load balance.
// 4 waves x 32 q-rows = 128 q-rows / block. XOR-swizzled sK/sV, padded sP.
__global__ __launch_bounds__(256) void attn_kernel(
    const unsigned short* __restrict__ qn, const unsigned short* __restrict__ kn,
    const unsigned short* __restrict__ vt, unsigned short* __restrict__ o_flat) {
  __shared__ unsigned short sK[64 * 64];
  __shared__ unsigned short sV[64 * 64];        // V^T tile: [d][j]
  __shared__ unsigned short sP[4][32 * 72];     // stride 72 shorts (144B, 16B-aligned)
  int t = threadIdx.x, lane = t & 63, wv = t >> 6;
  int l16 = lane & 15, quad = lane >> 4;
  int qb = 15 - (blockIdx.x >> 5);              // heavy tiles first
  int bh = blockIdx.x & 31;
  int m0 = qb * 128 + wv * 32;                  // wave's first q row (seq index)
  const unsigned short* qbase = qn + (size_t)bh * Nn * DHh;
  const unsigned short* kbase = kn + (size_t)bh * Nn * DHh;
  const unsigned short* vbase = vt + (size_t)bh * DHh * Nn;

  // Q fragments in registers for the whole K loop (q pre-scaled by 8)
  bf16x8 aq[2][2];
  #pragma unroll
  for (int i2 = 0; i2 < 2; i2++)
    #pragma unroll
    for (int kk = 0; kk < 2; kk++)
      aq[i2][kk] = *(const bf16x8*)(qbase + (size_t)(m0 + i2 * 16 + l16) * DHh + kk * 32 + quad * 8);

  f32x4 accO[2][4] = {};
  float den[2][4] = {};

  int srow = t >> 3;                     // 0..31
  int gch = (t & 7) ^ (srow & 7);        // swizzled chunk
  unsigned short* pw = sP[wv];
  int nkt = qb * 2 + 2;

  for (int kt = 0; kt < nkt; kt++) {
    int j0 = kt * 64;
    __syncthreads();
    GLDS16(kbase + (size_t)(j0 + srow)      * DHh + gch * 8, sK + (size_t)t * 8);
    GLDS16(kbase + (size_t)(j0 + srow + 32) * DHh + gch * 8, sK + (size_t)(t + 256) * 8);
    GLDS16(vbase + (size_t)srow        * Nn + j0 + gch * 8, sV + (size_t)t * 8);
    GLDS16(vbase + (size_t)(srow + 32) * Nn + j0 + gch * 8, sV + (size_t)(t + 256) * 8);
    __syncthreads();

    // S = Qn * Kn^T   (32 q-rows x 64 j per wave)
    f32x4 sc[2][4] = {};
    #pragma unroll
    for (int kk = 0; kk < 2; kk++) {
      int slot = (kk * 4 + quad) ^ (l16 & 7);
      #pragma unroll
      for (int jt = 0; jt < 4; jt++) {
        bf16x8 bk = *(const bf16x8*)(sK + (size_t)(jt * 16 + l16) * 64 + slot * 8);
        #pragma unroll
        for (int i2 = 0; i2 < 2; i2++)
          sc[i2][jt] = __builtin_amdgcn_mfma_f32_16x16x32_bf16(aq[i2][kk], bk, sc[i2][jt], 0, 0, 0);
      }
    }

    // exp(s-8), mask (only on non-full tiles), den accumulate, write P to LDS
    bool fullTile = (j0 + 63) <= m0;     // wave-uniform
    #pragma unroll
    for (int i2 = 0; i2 < 2; i2++) {
      #pragma unroll
      for (int jt = 0; jt < 4; jt++) {
        int j = j0 + jt * 16 + l16;
        #pragma unroll
        for (int r = 0; r < 4; r++) {
          float p;
          if (fullTile) {
            p = __expf(sc[i2][jt][r] - 8.0f);
          } else {
            int qrow = m0 + i2 * 16 + quad * 4 + r;
            p = (j <= qrow) ? __expf(sc[i2][jt][r] - 8.0f) : 0.0f;
          }
          den[i2][r] += p;
          pw[(i2 * 16 + quad * 4 + r) * 72 + jt * 16 + l16] = f2bf_fast(p);
        }
      }
    }
    // no barrier needed: sP is wave-private, same-wave LDS ordering is lgkmcnt

    // O += P * V  (P from LDS A-layout, V^T from LDS B-layout)
    #pragma unroll
    for (int kk = 0; kk < 2; kk++) {
      int slot = (kk * 4 + quad) ^ (l16 & 7);
      bf16x8 pa[2];
      #pragma unroll
      for (int i2 = 0; i2 < 2; i2++)
        pa[i2] = *(const bf16x8*)(pw + (size_t)(i2 * 16 + l16) * 72 + kk * 32 + quad * 8);
      #pragma unroll
      for (int dt = 0; dt < 4; dt++) {
        bf16x8 bv = *(const bf16x8*)(sV + (size_t)(dt * 16 + l16) * 64 + slot * 8);
        #pragma unroll
        for (int i2 = 0; i2 < 2; i2++)
          accO[i2][dt] = __builtin_amdgcn_mfma_f32_16x16x32_bf16(pa[i2], bv, accO[i2][dt], 0, 0, 0);
      }
    }
  }

  // reduce den across the 16 lanes of each quad (j-direction)
  #pragma unroll
  for (int i2 = 0; i2 < 2; i2++)
    #pragma unroll
    for (int r = 0; r < 4; r++) {
      float d = den[i2][r];
      d += __shfl_xor(d, 1); d += __shfl_xor(d, 2);
      d += __shfl_xor(d, 4); d += __shfl_xor(d, 8);
      den[i2][r] = 1.0f / d;
    }

  // write O -> o_flat [B,N,DIM] bf16 (merge heads)
  int bi = bh >> 4, h = bh & 15;
  #pragma unroll
  for (int i2 = 0; i2 < 2; i2++)
    #pragma unroll
    for (int dt = 0; dt < 4; dt++)
      #pragma unroll
      for (int r = 0; r < 4; r++) {
        int ns = m0 + i2 * 16 + quad * 4 + r;
        o_flat[((size_t)(bi * Nn + ns)) * DIMM + h * DHh + dt * 16 + l16] =
            f2bf(accO[i2][dt][r] * den[i2][r]);
      }
}

// ---------------------------------------------------------------------------
extern "C" void kernel_launch(void* const* d_in, const int* in_sizes, int n_in,
                              void* d_out, int out_size, void* d_ws, size_t ws_size,
                              hipStream_t stream) {
  const float* x        = (const float*)d_in[0];
  const float* g        = (const float*)d_in[1];
  const float* b        = (const float*)d_in[2];
  const float* c_attn_w = (const float*)d_in[3];
  const float* c_attn_b = (const float*)d_in[4];
  const float* c_proj_w = (const float*)d_in[5];
  const float* c_proj_b = (const float*)d_in[6];
  const float* to_out_w = (const float*)d_in[7];
  float* out = (float*)d_out;

  char* p = (char*)d_ws;
  unsigned short* y     = (unsigned short*)(p + ((size_t)0  << 20)); // 8 MB (also o_flat)
  unsigned short* qbuf  = (unsigned short*)(p + ((size_t)8  << 20)); // 8 MB
  unsigned short* kbuf  = (unsigned short*)(p + ((size_t)16 << 20)); // 8 MB
  unsigned short* vbuf  = (unsigned short*)(p + ((size_t)24 << 20)); // 8 MB
  unsigned short* vtb   = (unsigned short*)(p + ((size_t)32 << 20)); // 8 MB (after wpbf/wout dead)
  unsigned short* wpbf  = (unsigned short*)(p + ((size_t)32 << 20)); // 2 MB (dead before vtb)
  unsigned short* wout  = (unsigned short*)(p + ((size_t)34 << 20)); // 2 MB (dead before vtb)
  unsigned short* wqkv  = (unsigned short*)(p + ((size_t)40 << 20)); // 6 MB
  unsigned short* wcomb = (unsigned short*)(p + ((size_t)46 << 20)); // 2 MB
  float*          bc    = (float*)        (p + ((size_t)48 << 20)); // 4 KB

  // 1. LayerNorm -> y (bf16)
  ln_kernel<<<MROWS, 256, 0, stream>>>(x, g, b, y);
  // 2. weight prep
  transpose_conv<<<dim3(3 * DIMM / 32, DIMM / 32), dim3(32, 8), 0, stream>>>(c_attn_w, wqkv, DIMM, 3 * DIMM);
  convert_bf<<<(DIMM * DIMM) / (256 * 4), 256, 0, stream>>>(c_proj_w, wpbf);  // [j][c]
  convert_bf<<<(DIMM * DIMM) / (256 * 4), 256, 0, stream>>>(to_out_w, wout);  // [n][c]
  bias_comb<<<DIMM / 4, 256, 0, stream>>>(c_proj_b, to_out_w, bc);
  // 3. combined weight: wcomb[n][j] = sum_c Wo[n][c] * Wp[j][c]
  gemm_nt<3><<<dim3(DIMM / 128, DIMM / 128), 256, 0, stream>>>(
      wout, wpbf, nullptr, wcomb, nullptr, nullptr, nullptr, nullptr, DIMM, DIMM, DIMM);
  // 4. qkv GEMM + scatter + fused l2norm (q*8, k)
  gemm_nt<0><<<dim3(3 * DIMM / 128, MROWS / 128), 256, 0, stream>>>(
      y, wqkv, c_attn_b, nullptr, nullptr, qbuf, kbuf, vbuf, MROWS, 3 * DIMM, DIMM);
  // 5. V transpose (overwrites wpbf/wout region — both dead now)
  transpose_v<<<dim3(DHh / 32, Nn / 32, BH), dim3(32, 8), 0, stream>>>(vbuf, vtb);
  // 6. attention -> o_flat (reuses y)
  attn_kernel<<<512, 256, 0, stream>>>(qbuf, kbuf, vtb, y);
  // 7. fused (c_proj ∘ to_out): out = o_flat @ wcomb^T + bc  (fp32)
  gemm_nt<2><<<dim3(DIMM / 128, MROWS / 128), 256, 0, stream>>>(
      y, wcomb, bc, nullptr, out, nullptr, nullptr, nullptr, MROWS, DIMM, DIMM);
}

// Round 3
// 248.715 us; speedup vs baseline: 1.2498x; 1.0538x over previous
//
#include <hip/hip_runtime.h>
#include <cstdint>
#include <cstddef>

// Problem constants
#define Bb 2
#define Nn 2048
#define DIMM 1024
#define Hh 16
#define DHh 64
#define BH (Bb*Hh)        // 32
#define MROWS (Bb*Nn)     // 4096

typedef __bf16 bf16x8 __attribute__((ext_vector_type(8)));
typedef float f32x4 __attribute__((ext_vector_type(4)));
typedef short s16x4 __attribute__((ext_vector_type(4)));

__device__ __forceinline__ unsigned short f2bf(float f) {
  unsigned u = __float_as_uint(f);
  u += 0x7FFFu + ((u >> 16) & 1u);       // RNE
  return (unsigned short)(u >> 16);
}
__device__ __forceinline__ unsigned short f2bf_fast(float f) {
  return (unsigned short)((__float_as_uint(f) + 0x8000u) >> 16);
}
__device__ __forceinline__ float bf2f(unsigned short s) {
  return __uint_as_float(((unsigned)s) << 16);
}

// async global->LDS, 16B per lane; LDS dest must be wave-uniform base + lane*16
#define GLDS16(g, l) __builtin_amdgcn_global_load_lds( \
    (const __attribute__((address_space(1))) void*)(g), \
    (__attribute__((address_space(3))) void*)(l), 16, 0, 0)

// ---------------------------------------------------------------------------
// LayerNorm: x fp32 [4096,1024] -> y bf16. One block per row.
__global__ __launch_bounds__(256) void ln_kernel(
    const float* __restrict__ x, const float* __restrict__ g,
    const float* __restrict__ b, unsigned short* __restrict__ y) {
  int row = blockIdx.x;
  int t = threadIdx.x;
  const float4* xr = (const float4*)(x + (size_t)row * DIMM);
  float4 v = xr[t];
  float s  = v.x + v.y + v.z + v.w;
  float ss = v.x*v.x + v.y*v.y + v.z*v.z + v.w*v.w;
  #pragma unroll
  for (int o = 1; o < 64; o <<= 1) { s += __shfl_xor(s, o); ss += __shfl_xor(ss, o); }
  __shared__ float red[8];
  int wv = t >> 6;
  if ((t & 63) == 0) { red[wv] = s; red[wv + 4] = ss; }
  __syncthreads();
  s  = red[0] + red[1] + red[2] + red[3];
  ss = red[4] + red[5] + red[6] + red[7];
  float mu  = s * (1.0f / DIMM);
  float var = ss * (1.0f / DIMM) - mu * mu;
  float rs  = rsqrtf(var + 1e-5f);
  float4 gv = ((const float4*)g)[t];
  float4 bv = ((const float4*)b)[t];
  ushort4 o4;
  o4.x = f2bf((v.x - mu) * rs * gv.x + bv.x);
  o4.y = f2bf((v.y - mu) * rs * gv.y + bv.y);
  o4.z = f2bf((v.z - mu) * rs * gv.z + bv.z);
  o4.w = f2bf((v.w - mu) * rs * gv.w + bv.w);
  ((ushort4*)y)[(size_t)row * 256 + t] = o4;
}

// ---------------------------------------------------------------------------
// Transpose + fp32->bf16: in [R][C] -> out [C][R]
__global__ void transpose_conv(const float* __restrict__ in,
                               unsigned short* __restrict__ out, int R, int C) {
  __shared__ float tile[32][33];
  int tx = threadIdx.x, ty = threadIdx.y;
  int x  = blockIdx.x * 32 + tx;
  int y0 = blockIdx.y * 32;
  #pragma unroll
  for (int j = 0; j < 32; j += 8)
    tile[ty + j][tx] = in[(size_t)(y0 + ty + j) * C + x];
  __syncthreads();
  int ox  = blockIdx.y * 32 + tx;
  int oy0 = blockIdx.x * 32;
  #pragma unroll
  for (int j = 0; j < 32; j += 8)
    out[(size_t)(oy0 + ty + j) * R + ox] = f2bf(tile[tx][ty + j]);
}

// Elementwise fp32->bf16
__global__ void convert_bf(const float* __restrict__ in, unsigned short* __restrict__ out) {
  int i = (blockIdx.x * blockDim.x + threadIdx.x) * 4;
  float4 v = *(const float4*)(in + i);
  ushort4 o;
  o.x = f2bf(v.x); o.y = f2bf(v.y); o.z = f2bf(v.z); o.w = f2bf(v.w);
  *(ushort4*)(out + i) = o;
}

// Combined bias: bc[n] = sum_c bp[c] * Wo[n][c]   (fp32). One wave per n.
__global__ __launch_bounds__(256) void bias_comb(
    const float* __restrict__ bp, const float* __restrict__ wo,
    float* __restrict__ bc) {
  int n = blockIdx.x * 4 + (threadIdx.x >> 6);
  int lane = threadIdx.x & 63;
  const float4* w = (const float4*)(wo + (size_t)n * DIMM);
  const float4* b4 = (const float4*)bp;
  float s = 0.0f;
  #pragma unroll
  for (int k = 0; k < 4; k++) {
    float4 wv = w[lane + k * 64], bv = b4[lane + k * 64];
    s += wv.x * bv.x + wv.y * bv.y + wv.z * bv.z + wv.w * bv.w;
  }
  #pragma unroll
  for (int o = 1; o < 64; o <<= 1) s += __shfl_xor(s, o);
  if (lane == 0) bc[n] = s;
}

// ---------------------------------------------------------------------------
// NT GEMM: C[M,N] = A[M,K] * Bt[N,K]^T (+bias). 128x128 tile, BK=64, 4 waves.
// XOR-swizzled LDS (chunk ^= row&7) to kill bank conflicts.
// EPI 0: scatter qkv -> q/k/v [B,H,N,DH] bf16, with fused L2-norm (q*8, k)
// EPI 2: fp32 out [M,N] + bias
// EPI 3: bf16 out [M,N], no bias
template <int EPI>
__global__ __launch_bounds__(256) void gemm_nt(
    const unsigned short* __restrict__ A, const unsigned short* __restrict__ Bt,
    const float* __restrict__ bias,
    unsigned short* __restrict__ obf, float* __restrict__ of32,
    unsigned short* __restrict__ q_std, unsigned short* __restrict__ k_std,
    unsigned short* __restrict__ v_std,
    int M, int N, int K) {
  __shared__ unsigned short sA[128 * 64];
  __shared__ unsigned short sB[128 * 64];
  int t = threadIdx.x;
  int bn = blockIdx.x, bm = blockIdx.y;
  int lane = t & 63, wv = t >> 6;
  int wm = (wv >> 1) * 64, wn = (wv & 1) * 64;
  int l16 = lane & 15, quad = lane >> 4;

  const unsigned short* Ab = A + (size_t)(bm * 128) * K;
  const unsigned short* Bb2 = Bt + (size_t)(bn * 128) * K;
  int srow = t >> 3;                     // 0..31
  int gch = (t & 7) ^ (srow & 7);        // swizzled global chunk for this lane

  f32x4 acc[4][4] = {};

  for (int kt = 0; kt < K; kt += 64) {
    __syncthreads();
    #pragma unroll
    for (int i = 0; i < 4; i++) {
      GLDS16(Ab  + (size_t)(srow + 32 * i) * K + kt + gch * 8, sA + (size_t)(t + 256 * i) * 8);
      GLDS16(Bb2 + (size_t)(srow + 32 * i) * K + kt + gch * 8, sB + (size_t)(t + 256 * i) * 8);
    }
    __syncthreads();
    #pragma unroll
    for (int kk = 0; kk < 2; kk++) {
      int slot = (kk * 4 + quad) ^ (l16 & 7);
      bf16x8 af[4], bfr[4];
      #pragma unroll
      for (int i = 0; i < 4; i++)
        af[i] = *(const bf16x8*)(sA + (size_t)(wm + i * 16 + l16) * 64 + slot * 8);
      #pragma unroll
      for (int j = 0; j < 4; j++)
        bfr[j] = *(const bf16x8*)(sB + (size_t)(wn + j * 16 + l16) * 64 + slot * 8);
      #pragma unroll
      for (int i = 0; i < 4; i++)
        #pragma unroll
        for (int j = 0; j < 4; j++)
          acc[i][j] = __builtin_amdgcn_mfma_f32_16x16x32_bf16(af[i], bfr[j], acc[i][j], 0, 0, 0);
    }
  }

  // epilogue: D row = quad*4+reg, col = l16
  float bvals[4];
  #pragma unroll
  for (int j = 0; j < 4; j++)
    bvals[j] = (EPI == 3) ? 0.0f : bias[bn * 128 + wn + j * 16 + l16];

  if (EPI == 0) {
    int which = bn >> 3;                 // 0=q 1=k 2=v  (bn*128/1024)
    #pragma unroll
    for (int i = 0; i < 4; i++) {
      #pragma unroll
      for (int r = 0; r < 4; r++) {
        int m = bm * 128 + wm + i * 16 + quad * 4 + r;
        float vals[4];
        float ss = 0.0f;
        #pragma unroll
        for (int j = 0; j < 4; j++) {
          vals[j] = acc[i][j][r] + bvals[j];
          ss += vals[j] * vals[j];
        }
        float scale = 1.0f;
        if (which < 2) {
          ss += __shfl_xor(ss, 1); ss += __shfl_xor(ss, 2);
          ss += __shfl_xor(ss, 4); ss += __shfl_xor(ss, 8);
          scale = ((which == 0) ? 8.0f : 1.0f) / fmaxf(sqrtf(ss), 1e-12f);
        }
        int bi = m >> 11, ns = m & 2047;
        unsigned short* dst = (which == 0) ? q_std : ((which == 1) ? k_std : v_std);
        #pragma unroll
        for (int j = 0; j < 4; j++) {
          int n = bn * 128 + wn + j * 16 + l16;
          int nn2 = n & 1023;
          int h = nn2 >> 6, d = nn2 & 63;
          dst[((size_t)((bi * Hh + h) * Nn + ns)) * DHh + d] = f2bf(vals[j] * scale);
        }
      }
    }
  } else {
    #pragma unroll
    for (int i = 0; i < 4; i++) {
      #pragma unroll
      for (int j = 0; j < 4; j++) {
        int n = bn * 128 + wn + j * 16 + l16;
        #pragma unroll
        for (int r = 0; r < 4; r++) {
          int m = bm * 128 + wm + i * 16 + quad * 4 + r;
          float val = acc[i][j][r] + bvals[j];
          if (EPI == 2) of32[(size_t)m * N + n] = val;
          else          obf[(size_t)m * N + n] = f2bf(val);
        }
      }
    }
  }
}

// ---------------------------------------------------------------------------
// Transpose V: [B,H,N,DH] -> [B,H,DH,N] (bf16)
__global__ void transpose_v(const unsigned short* __restrict__ v,
                            unsigned short* __restrict__ vt) {
  __shared__ unsigned short tile[32][33];
  int bh = blockIdx.z;
  const unsigned short* in = v + (size_t)bh * Nn * DHh;
  unsigned short* out = vt + (size_t)bh * DHh * Nn;
  int tx = threadIdx.x, ty = threadIdx.y;
  int x = blockIdx.x * 32 + tx;        // d
  int y0 = blockIdx.y * 32;            // n
  #pragma unroll
  for (int j = 0; j < 32; j += 8)
    tile[ty + j][tx] = in[(size_t)(y0 + ty + j) * DHh + x];
  __syncthreads();
  int ox = blockIdx.y * 32 + tx;       // n
  int oy0 = blockIdx.x * 32;           // d
  #pragma unroll
  for (int j = 0; j < 32; j += 8)
    out[(size_t)(oy0 + ty + j) * Nn + ox] = tile[tx][ty + j];
}

// ---------------------------------------------------------------------------
// Causal cosine-sim attention, register-resident P:
//   S^T = K·Q^T via mfma(A=K, B=Q)  -> C-layout row=j, col=m
//   P^T (exp'd, bf16) is directly the B-operand of 16x16x16 MFMA
//   O^T[d][m] += V^T[d][j] · P^T[j][m]
// Grid: 512 blocks, paired ordering (heavy+light co-resident). 4 waves x 32 q.
__global__ __launch_bounds__(256, 2) void attn_kernel(
    const unsigned short* __restrict__ qn, const unsigned short* __restrict__ kn,
    const unsigned short* __restrict__ vt, unsigned short* __restrict__ o_flat) {
  __shared__ unsigned short sK[64 * 64];
  __shared__ unsigned short sV[64 * 64];        // V^T tile: [d][j], swizzled
  int t = threadIdx.x, lane = t & 63, wv = t >> 6;
  int l16 = lane & 15, quad = lane >> 4;
  int id = blockIdx.x;
  int qb = (id < 256) ? (15 - (id >> 5)) : ((id - 256) >> 5);  // pair heavy+light
  int bh = id & 31;
  int m0 = qb * 128 + wv * 32;                  // wave's first q row (seq index)
  const unsigned short* qbase = qn + (size_t)bh * Nn * DHh;
  const unsigned short* kbase = kn + (size_t)bh * Nn * DHh;
  const unsigned short* vbase = vt + (size_t)bh * DHh * Nn;

  // Q fragments (q pre-scaled by 8); same lane layout serves as MFMA B-operand
  bf16x8 aq[2][2];
  #pragma unroll
  for (int i2 = 0; i2 < 2; i2++)
    #pragma unroll
    for (int kk = 0; kk < 2; kk++)
      aq[i2][kk] = *(const bf16x8*)(qbase + (size_t)(m0 + i2 * 16 + l16) * DHh + kk * 32 + quad * 8);

  f32x4 accOT[4][2] = {};       // [dt][i2]: O^T, row=d=quad*4+r, col=m=l16
  float den[2] = {};            // per-lane partial: m = i2*16+l16 (quad-partial)

  int srow = t >> 3;                     // 0..31
  int gch = (t & 7) ^ (srow & 7);        // swizzled chunk
  int nkt = qb * 2 + 2;

  for (int kt = 0; kt < nkt; kt++) {
    int j0 = kt * 64;
    __syncthreads();
    GLDS16(kbase + (size_t)(j0 + srow)      * DHh + gch * 8, sK + (size_t)t * 8);
    GLDS16(kbase + (size_t)(j0 + srow + 32) * DHh + gch * 8, sK + (size_t)(t + 256) * 8);
    GLDS16(vbase + (size_t)srow        * Nn + j0 + gch * 8, sV + (size_t)t * 8);
    GLDS16(vbase + (size_t)(srow + 32) * Nn + j0 + gch * 8, sV + (size_t)(t + 256) * 8);
    __syncthreads();

    if (j0 > m0 + 31) continue;          // fully masked for this wave (uniform)

    // S^T = K·Q^T : sc[jt][i2], row=j_local=quad*4+r, col=m_local=l16
    f32x4 sc[4][2] = {};
    #pragma unroll
    for (int kk = 0; kk < 2; kk++) {
      int slot = (kk * 4 + quad) ^ (l16 & 7);
      #pragma unroll
      for (int jt = 0; jt < 4; jt++) {
        bf16x8 ak = *(const bf16x8*)(sK + (size_t)(jt * 16 + l16) * 64 + slot * 8);
        #pragma unroll
        for (int i2 = 0; i2 < 2; i2++)
          sc[jt][i2] = __builtin_amdgcn_mfma_f32_16x16x32_bf16(ak, aq[i2][kk], sc[jt][i2], 0, 0, 0);
      }
    }

    // exp(s-8) in-register; P^T bf16 is directly the 16x16x16 B-operand
    bool fullTile = (j0 + 63) <= m0;     // wave-uniform
    s16x4 pf[4][2];
    #pragma unroll
    for (int jt = 0; jt < 4; jt++) {
      #pragma unroll
      for (int i2 = 0; i2 < 2; i2++) {
        int m = m0 + i2 * 16 + l16;
        #pragma unroll
        for (int r = 0; r < 4; r++) {
          int j = j0 + jt * 16 + quad * 4 + r;
          float p;
          if (fullTile) p = __expf(sc[jt][i2][r] - 8.0f);
          else          p = (j <= m) ? __expf(sc[jt][i2][r] - 8.0f) : 0.0f;
          den[i2] += p;
          pf[jt][i2][r] = (short)f2bf_fast(p);
        }
      }
    }

    // O^T += V^T · P^T   (A = V^T frag from LDS, 4 bf16/lane: [d=l16][j=quad*4+i])
    #pragma unroll
    for (int jt = 0; jt < 4; jt++) {
      #pragma unroll
      for (int dt = 0; dt < 4; dt++) {
        int row = dt * 16 + l16;
        int ch = (jt * 2 + (quad >> 1)) ^ (l16 & 7);
        s16x4 av = *(const s16x4*)(sV + (size_t)row * 64 + ch * 8 + (quad & 1) * 4);
        #pragma unroll
        for (int i2 = 0; i2 < 2; i2++)
          accOT[dt][i2] = __builtin_amdgcn_mfma_f32_16x16x16bf16_1k(av, pf[jt][i2], accOT[dt][i2], 0, 0, 0);
      }
    }
  }

  // reduce den across quads (j-direction lives on lane>>4)
  #pragma unroll
  for (int i2 = 0; i2 < 2; i2++) {
    float d = den[i2];
    d += __shfl_xor(d, 16); d += __shfl_xor(d, 32);
    den[i2] = 1.0f / d;
  }

  // write O^T -> o_flat [B,N,DIM] bf16: lane(quad,l16) reg r holds
  // O[d = dt*16+quad*4+r][m = i2*16+l16]
  int bi = bh >> 4, h = bh & 15;
  #pragma unroll
  for (int i2 = 0; i2 < 2; i2++) {
    #pragma unroll
    for (int dt = 0; dt < 4; dt++) {
      ushort4 o4;
      float dinv = den[i2];
      o4.x = f2bf(accOT[dt][i2][0] * dinv);
      o4.y = f2bf(accOT[dt][i2][1] * dinv);
      o4.z = f2bf(accOT[dt][i2][2] * dinv);
      o4.w = f2bf(accOT[dt][i2][3] * dinv);
      int ns = m0 + i2 * 16 + l16;
      int d0 = dt * 16 + quad * 4;
      *(ushort4*)(o_flat + ((size_t)(bi * Nn + ns)) * DIMM + h * DHh + d0) = o4;
    }
  }
}

// ---------------------------------------------------------------------------
extern "C" void kernel_launch(void* const* d_in, const int* in_sizes, int n_in,
                              void* d_out, int out_size, void* d_ws, size_t ws_size,
                              hipStream_t stream) {
  const float* x        = (const float*)d_in[0];
  const float* g        = (const float*)d_in[1];
  const float* b        = (const float*)d_in[2];
  const float* c_attn_w = (const float*)d_in[3];
  const float* c_attn_b = (const float*)d_in[4];
  const float* c_proj_w = (const float*)d_in[5];
  const float* c_proj_b = (const float*)d_in[6];
  const float* to_out_w = (const float*)d_in[7];
  float* out = (float*)d_out;

  char* p = (char*)d_ws;
  unsigned short* y     = (unsigned short*)(p + ((size_t)0  << 20)); // 8 MB (also o_flat)
  unsigned short* qbuf  = (unsigned short*)(p + ((size_t)8  << 20)); // 8 MB
  unsigned short* kbuf  = (unsigned short*)(p + ((size_t)16 << 20)); // 8 MB
  unsigned short* vbuf  = (unsigned short*)(p + ((size_t)24 << 20)); // 8 MB
  unsigned short* vtb   = (unsigned short*)(p + ((size_t)32 << 20)); // 8 MB (after wpbf/wout dead)
  unsigned short* wpbf  = (unsigned short*)(p + ((size_t)32 << 20)); // 2 MB (dead before vtb)
  unsigned short* wout  = (unsigned short*)(p + ((size_t)34 << 20)); // 2 MB (dead before vtb)
  unsigned short* wqkv  = (unsigned short*)(p + ((size_t)40 << 20)); // 6 MB
  unsigned short* wcomb = (unsigned short*)(p + ((size_t)46 << 20)); // 2 MB
  float*          bc    = (float*)        (p + ((size_t)48 << 20)); // 4 KB

  // 1. LayerNorm -> y (bf16)
  ln_kernel<<<MROWS, 256, 0, stream>>>(x, g, b, y);
  // 2. weight prep
  transpose_conv<<<dim3(3 * DIMM / 32, DIMM / 32), dim3(32, 8), 0, stream>>>(c_attn_w, wqkv, DIMM, 3 * DIMM);
  convert_bf<<<(DIMM * DIMM) / (256 * 4), 256, 0, stream>>>(c_proj_w, wpbf);  // [j][c]
  convert_bf<<<(DIMM * DIMM) / (256 * 4), 256, 0, stream>>>(to_out_w, wout);  // [n][c]
  bias_comb<<<DIMM / 4, 256, 0, stream>>>(c_proj_b, to_out_w, bc);
  // 3. combined weight: wcomb[n][j] = sum_c Wo[n][c] * Wp[j][c]
  gemm_nt<3><<<dim3(DIMM / 128, DIMM / 128), 256, 0, stream>>>(
      wout, wpbf, nullptr, wcomb, nullptr, nullptr, nullptr, nullptr, DIMM, DIMM, DIMM);
  // 4. qkv GEMM + scatter + fused l2norm (q*8, k)
  gemm_nt<0><<<dim3(3 * DIMM / 128, MROWS / 128), 256, 0, stream>>>(
      y, wqkv, c_attn_b, nullptr, nullptr, qbuf, kbuf, vbuf, MROWS, 3 * DIMM, DIMM);
  // 5. V transpose (overwrites wpbf/wout region — both dead now)
  transpose_v<<<dim3(DHh / 32, Nn / 32, BH), dim3(32, 8), 0, stream>>>(vbuf, vtb);
  // 6. attention -> o_flat (reuses y)
  attn_kernel<<<512, 256, 0, stream>>>(qbuf, kbuf, vtb, y);
  // 7. fused (c_proj ∘ to_out): out = o_flat @ wcomb^T + bc  (fp32)
  gemm_nt<2><<<dim3(DIMM / 128, MROWS / 128), 256, 0, stream>>>(
      y, wcomb, bc, nullptr, out, nullptr, nullptr, nullptr, MROWS, DIMM, DIMM);
}